// Round 1
// baseline (1173.628 us; speedup 1.0000x reference)
//
#include <hip/hip_runtime.h>
#include <hip/hip_bf16.h>
#include <cstdint>

#define NE 8
#define DM 1024
#define DFF 4096
#define PD 256
#define NTOK 8192
#define MAXMB 136            // sum_e ceil(T_e/128) <= 16384/128 + 7 = 135
#define MAXROWS (MAXMB * 128)

typedef __attribute__((ext_vector_type(8))) short bf16x8;
typedef __attribute__((ext_vector_type(4))) float floatx4;
typedef unsigned short u16;

__device__ __forceinline__ u16 f2bf(float f) {
  unsigned int u = __float_as_uint(f);
  unsigned int r = (u + 0x7FFFu + ((u >> 16) & 1u)) >> 16;  // RNE
  return (u16)r;
}

__device__ __forceinline__ void async_ld16(const void* g, void* l) {
  __builtin_amdgcn_global_load_lds(
      (__attribute__((address_space(1))) unsigned int*)g,
      (__attribute__((address_space(3))) unsigned int*)l, 16, 0, 0);
}

// ---------------- fp32 -> bf16 convert (grid-stride, float4) ----------------
__global__ void convert_kernel(const float4* __restrict__ src,
                               ushort4* __restrict__ dst, int n4) {
  int i = blockIdx.x * blockDim.x + threadIdx.x;
  int stride = gridDim.x * blockDim.x;
  for (; i < n4; i += stride) {
    float4 v = src[i];
    ushort4 o;
    o.x = f2bf(v.x); o.y = f2bf(v.y); o.z = f2bf(v.z); o.w = f2bf(v.w);
    dst[i] = o;
  }
}

// ---------------- fp32 proj GEMM: proj = x @ cosw^T + cosb ----------------
// x [8192,1024], cosw [256,1024] (B^T form), proj [8192,256]
__global__ __launch_bounds__(256, 2) void proj_gemm(
    const float* __restrict__ x, const float* __restrict__ w,
    const float* __restrict__ b, float* __restrict__ proj) {
  __shared__ float Ats[32][68];  // [k][m], stride 68 floats (16B-aligned rows)
  __shared__ float Bts[32][68];  // [k][n]
  const int m0 = blockIdx.x * 64;
  const int n0 = blockIdx.y * 64;
  const int tid = threadIdx.x;
  const int tn = tid & 15, tm = tid >> 4;
  float acc[4][4] = {};
  for (int k0 = 0; k0 < DM; k0 += 32) {
#pragma unroll
    for (int u = 0; u < 2; u++) {
      int idx = tid + u * 256;
      int row = idx >> 3, kq = (idx & 7) * 4;
      float4 va = *(const float4*)&x[(size_t)(m0 + row) * DM + k0 + kq];
      Ats[kq + 0][row] = va.x; Ats[kq + 1][row] = va.y;
      Ats[kq + 2][row] = va.z; Ats[kq + 3][row] = va.w;
      float4 vb = *(const float4*)&w[(size_t)(n0 + row) * DM + k0 + kq];
      Bts[kq + 0][row] = vb.x; Bts[kq + 1][row] = vb.y;
      Bts[kq + 2][row] = vb.z; Bts[kq + 3][row] = vb.w;
    }
    __syncthreads();
#pragma unroll
    for (int kk = 0; kk < 32; kk++) {
      float4 av = *(const float4*)&Ats[kk][tm * 4];
      float4 bv = *(const float4*)&Bts[kk][tn * 4];
      float ar[4] = {av.x, av.y, av.z, av.w};
      float br[4] = {bv.x, bv.y, bv.z, bv.w};
#pragma unroll
      for (int i = 0; i < 4; i++)
#pragma unroll
        for (int j = 0; j < 4; j++) acc[i][j] = fmaf(ar[i], br[j], acc[i][j]);
    }
    __syncthreads();
  }
#pragma unroll
  for (int i = 0; i < 4; i++) {
    int row = m0 + tm * 4 + i;
#pragma unroll
    for (int j = 0; j < 4; j++) {
      int col = n0 + tn * 4 + j;
      proj[(size_t)row * PD + col] = acc[i][j] + b[col];
    }
  }
}

// ---------------- sim_matrix column l2norm: simn[p][e] ----------------
__global__ void simnorm_kernel(const float* __restrict__ sim,
                               float* __restrict__ simn) {
  __shared__ float partial[256];
  __shared__ float norms[8];
  int tid = threadIdx.x;
  int e = tid & 7, pg = tid >> 3;  // 32 p-groups
  float s = 0.f;
#pragma unroll
  for (int i = 0; i < 8; i++) {
    float v = sim[(size_t)(pg + i * 32) * NE + e];
    s += v * v;
  }
  partial[tid] = s;
  __syncthreads();
  if (tid < 8) {
    float t = 0.f;
    for (int g = 0; g < 32; g++) t += partial[tid + 8 * g];
    norms[tid] = fmaxf(sqrtf(t), 1e-12f);
  }
  __syncthreads();
  for (int i = tid; i < PD * NE; i += 256) simn[i] = sim[i] / norms[i & 7];
}

// ---------------- gate: l2norm(proj) . simn * exp(T), top-2 softmax ----------------
__global__ void gate_kernel(const float* __restrict__ proj,
                            const float* __restrict__ simn,
                            const float* __restrict__ temp,
                            int* __restrict__ tok_e, float* __restrict__ tok_g,
                            int* __restrict__ counts) {
  int t = blockIdx.x * 4 + (threadIdx.x >> 6);
  int lane = threadIdx.x & 63;
  float4 v = *(const float4*)&proj[(size_t)t * PD + lane * 4];
  float nn = v.x * v.x + v.y * v.y + v.z * v.z + v.w * v.w;
#pragma unroll
  for (int o = 32; o; o >>= 1) nn += __shfl_xor(nn, o);
  float inv = 1.0f / fmaxf(sqrtf(nn), 1e-12f);
  float l[8];
  int p = lane * 4;
#pragma unroll
  for (int e = 0; e < 8; e++) {
    float s = v.x * simn[(size_t)p * NE + e] + v.y * simn[(size_t)(p + 1) * NE + e] +
              v.z * simn[(size_t)(p + 2) * NE + e] + v.w * simn[(size_t)(p + 3) * NE + e];
#pragma unroll
    for (int o = 32; o; o >>= 1) s += __shfl_xor(s, o);
    l[e] = s;
  }
  if (lane == 0) {
    float scale = inv * expf(temp[0]);
    float ll[8];
#pragma unroll
    for (int e = 0; e < 8; e++) ll[e] = l[e] * scale;
    int i0 = 0;
    float best = ll[0];
#pragma unroll
    for (int e = 1; e < 8; e++)
      if (ll[e] > best) { best = ll[e]; i0 = e; }
    int i1 = -1;
    float second = -1e30f;
#pragma unroll
    for (int e = 0; e < 8; e++)
      if (e != i0 && ll[e] > second) { second = ll[e]; i1 = e; }
    float ex = expf(second - best);
    float g0 = 1.f / (1.f + ex);
    float g1 = ex / (1.f + ex);
    tok_e[t * 2] = i0; tok_e[t * 2 + 1] = i1;
    tok_g[t * 2] = g0; tok_g[t * 2 + 1] = g1;
    atomicAdd(&counts[i0], 1);
    atomicAdd(&counts[i1], 1);
  }
}

// ---------------- scan: 128-aligned expert segments + mb map ----------------
__global__ void scan_kernel(const int* __restrict__ counts,
                            int* __restrict__ cursors,
                            int* __restrict__ mb_expert,
                            int* __restrict__ total_mb) {
  if (threadIdx.x == 0 && blockIdx.x == 0) {
    int mb = 0;
    for (int e = 0; e < NE; e++) {
      cursors[e] = mb * 128;
      int c = (counts[e] + 127) >> 7;
      for (int i = 0; i < c; i++) mb_expert[mb + i] = e;
      mb += c;
    }
    *total_mb = mb;
  }
}

// ---------------- fill: slot assignment + gather x -> bf16 Xg ----------------
__global__ void fill_gather(const float* __restrict__ x,
                            const int* __restrict__ tok_e,
                            const float* __restrict__ tok_g,
                            int* __restrict__ cursors,
                            int* __restrict__ slot_token,
                            float* __restrict__ slot_gate,
                            u16* __restrict__ Xg) {
  int t = blockIdx.x;
  __shared__ int s_slot[2];
  if (threadIdx.x < 2) {
    int s = threadIdx.x;
    int e = tok_e[t * 2 + s];           // top-2 experts are distinct
    int slot = atomicAdd(&cursors[e], 1);
    s_slot[s] = slot;
    slot_token[slot] = t;
    slot_gate[slot] = tok_g[t * 2 + s];
  }
  __syncthreads();
  float4 xv = *(const float4*)&x[(size_t)t * DM + threadIdx.x * 4];
  ushort4 bv;
  bv.x = f2bf(xv.x); bv.y = f2bf(xv.y); bv.z = f2bf(xv.z); bv.w = f2bf(xv.w);
  *(ushort4*)&Xg[(size_t)s_slot[0] * DM + threadIdx.x * 4] = bv;
  *(ushort4*)&Xg[(size_t)s_slot[1] * DM + threadIdx.x * 4] = bv;
}

// ---------------- bf16 MFMA GEMM (m97-style 128x128xBK64, B^T weights) ----------------
// MODE 1: H = relu(A @ W[e]^T + bias[e])  -> bf16
// MODE 2: out[token] += gate * (A @ W[e]^T + bias[e])  (atomic scatter)
template <int KDIM, int MODE>
__global__ __launch_bounds__(256, 2) void moe_gemm(
    const u16* __restrict__ A, const u16* __restrict__ W,
    const float* __restrict__ bias, u16* __restrict__ Hout,
    float* __restrict__ Out, const int* __restrict__ mb_expert,
    const int* __restrict__ total_mb, const int* __restrict__ slot_token,
    const float* __restrict__ slot_gate, int NW) {
  const int mb = blockIdx.y;
  if (mb >= *total_mb) return;
  const int e = mb_expert[mb];
  const int nb = blockIdx.x;

  __shared__ u16 As[128 * 64];
  __shared__ u16 Bs[128 * 64];

  const int tid = threadIdx.x;
  const int lane = tid & 63;
  const int wv = tid >> 6;
  const int wm = wv >> 1, wn = wv & 1;

  const u16* Ab = A + (size_t)mb * 128 * KDIM;
  const u16* Bb = W + (size_t)e * NW * KDIM + (size_t)nb * 128 * KDIM;

  floatx4 acc[4][4] = {};

  const int r8 = lane >> 3;        // row within 8-row group
  const int c8 = (lane & 7) * 8;   // bf16-element col offset (16B chunks)

  for (int k0 = 0; k0 < KDIM; k0 += 64) {
#pragma unroll
    for (int i = 0; i < 4; i++) {
      int rowA = wv * 32 + i * 8;  // wave-uniform LDS base
      async_ld16(Ab + (size_t)(rowA + r8) * KDIM + k0 + c8, As + rowA * 64);
      async_ld16(Bb + (size_t)(rowA + r8) * KDIM + k0 + c8, Bs + rowA * 64);
    }
    __syncthreads();  // compiler emits vmcnt(0) drain before barrier
#pragma unroll
    for (int kk = 0; kk < 2; kk++) {
      const int kofs = kk * 32 + (lane >> 4) * 8;
      bf16x8 af[4], bfr[4];
#pragma unroll
      for (int i = 0; i < 4; i++)
        af[i] = *(const bf16x8*)(As + (wm * 64 + i * 16 + (lane & 15)) * 64 + kofs);
#pragma unroll
      for (int j = 0; j < 4; j++)
        bfr[j] = *(const bf16x8*)(Bs + (wn * 64 + j * 16 + (lane & 15)) * 64 + kofs);
#pragma unroll
      for (int i = 0; i < 4; i++)
#pragma unroll
        for (int j = 0; j < 4; j++)
          acc[i][j] = __builtin_amdgcn_mfma_f32_16x16x32_bf16(af[i], bfr[j],
                                                              acc[i][j], 0, 0, 0);
    }
    __syncthreads();
  }

  const int col0 = nb * 128 + wn * 64;
  const int row0 = mb * 128 + wm * 64;
  if constexpr (MODE == 1) {
#pragma unroll
    for (int j = 0; j < 4; j++) {
      int col = col0 + j * 16 + (lane & 15);
      float bv = bias[(size_t)e * NW + col];
#pragma unroll
      for (int i = 0; i < 4; i++)
#pragma unroll
        for (int r = 0; r < 4; r++) {
          int row = row0 + i * 16 + (lane >> 4) * 4 + r;
          float v = acc[i][j][r] + bv;
          Hout[(size_t)row * NW + col] = f2bf(fmaxf(v, 0.f));
        }
    }
  } else {
#pragma unroll
    for (int i = 0; i < 4; i++)
#pragma unroll
      for (int r = 0; r < 4; r++) {
        int row = row0 + i * 16 + (lane >> 4) * 4 + r;
        int tok = slot_token[row];
        float g = slot_gate[row];
        if (tok >= 0) {
#pragma unroll
          for (int j = 0; j < 4; j++) {
            int col = col0 + j * 16 + (lane & 15);
            atomicAdd(&Out[(size_t)tok * DM + col],
                      g * (acc[i][j][r] + bias[(size_t)e * NW + col]));
          }
        }
      }
  }
}

extern "C" void kernel_launch(void* const* d_in, const int* in_sizes, int n_in,
                              void* d_out, int out_size, void* d_ws, size_t ws_size,
                              hipStream_t stream) {
  const float* x = (const float*)d_in[0];
  const float* cosw = (const float*)d_in[1];
  const float* cosb = (const float*)d_in[2];
  const float* simm = (const float*)d_in[3];
  const float* temp = (const float*)d_in[4];
  const float* fc1w = (const float*)d_in[5];
  const float* fc1b = (const float*)d_in[6];
  const float* fc2w = (const float*)d_in[7];
  const float* fc2b = (const float*)d_in[8];
  float* out = (float*)d_out;

  char* ws = (char*)d_ws;
  size_t off = 0;
  auto alloc = [&](size_t bytes) {
    void* p = ws + off;
    off = (off + bytes + 255) & ~(size_t)255;
    return p;
  };
  u16* fc1w_bf = (u16*)alloc((size_t)NE * DFF * DM * 2);       // 64 MiB
  u16* fc2w_bf = (u16*)alloc((size_t)NE * DM * DFF * 2);       // 64 MiB
  u16* Xg = (u16*)alloc((size_t)MAXROWS * DM * 2);             // 34 MiB
  u16* H = (u16*)alloc((size_t)MAXROWS * DFF * 2);             // 136 MiB
  float* proj = (float*)alloc((size_t)NTOK * PD * 4);
  float* simn = (float*)alloc((size_t)PD * NE * 4);
  int* tok_e = (int*)alloc((size_t)NTOK * 2 * 4);
  float* tok_g = (float*)alloc((size_t)NTOK * 2 * 4);
  int* slot_token = (int*)alloc((size_t)MAXROWS * 4);
  float* slot_gate = (float*)alloc((size_t)MAXROWS * 4);
  int* counts = (int*)alloc(8 * 4);
  int* cursors = (int*)alloc(8 * 4);
  int* mb_expert = (int*)alloc(MAXMB * 4);
  int* total_mb = (int*)alloc(4);
  if (off > ws_size) return;  // workspace too small: fail loudly (wrong output)

  // init (ws/out are poisoned before every call)
  hipMemsetAsync(counts, 0, 32, stream);
  hipMemsetAsync(slot_token, 0xFF, (size_t)MAXROWS * 4, stream);      // -1
  hipMemsetAsync(Xg, 0, (size_t)MAXROWS * DM * 2, stream);            // zero pads
  hipMemsetAsync(out, 0, (size_t)NTOK * DM * 4, stream);

  // weights fp32 -> bf16
  convert_kernel<<<4096, 256, 0, stream>>>((const float4*)fc1w,
                                           (ushort4*)fc1w_bf, NE * DFF * DM / 4);
  convert_kernel<<<4096, 256, 0, stream>>>((const float4*)fc2w,
                                           (ushort4*)fc2w_bf, NE * DM * DFF / 4);

  // gate path (fp32 throughout: top-k selection must match fp32 reference)
  proj_gemm<<<dim3(NTOK / 64, PD / 64), 256, 0, stream>>>(x, cosw, cosb, proj);
  simnorm_kernel<<<1, 256, 0, stream>>>(simm, simn);
  gate_kernel<<<NTOK / 4, 256, 0, stream>>>(proj, simn, temp, tok_e, tok_g, counts);

  // routing
  scan_kernel<<<1, 1, 0, stream>>>(counts, cursors, mb_expert, total_mb);
  fill_gather<<<NTOK, 256, 0, stream>>>(x, tok_e, tok_g, cursors, slot_token,
                                        slot_gate, Xg);

  // expert FFN
  moe_gemm<DM, 1><<<dim3(DFF / 128, MAXMB), 256, 0, stream>>>(
      Xg, fc1w_bf, fc1b, H, nullptr, mb_expert, total_mb, nullptr, nullptr, DFF);
  moe_gemm<DFF, 2><<<dim3(DM / 128, MAXMB), 256, 0, stream>>>(
      H, fc2w_bf, fc2b, nullptr, out, mb_expert, total_mb, slot_token, slot_gate, DM);
}

// Round 4
// 1114.416 us; speedup vs baseline: 1.0531x; 1.0531x over previous
//
#include <hip/hip_runtime.h>
#include <hip/hip_bf16.h>
#include <cstdint>

#define NE 8
#define DM 1024
#define DFF 4096
#define PD 256
#define NTOK 8192
#define MAXMB 136            // sum_e ceil(T_e/128) <= 16384/128 + 7 = 135
#define MAXROWS (MAXMB * 128)

typedef __attribute__((ext_vector_type(8))) short bf16x8;
typedef __attribute__((ext_vector_type(4))) float floatx4;
typedef unsigned short u16;

__device__ __forceinline__ u16 f2bf(float f) {
  unsigned int u = __float_as_uint(f);
  unsigned int r = (u + 0x7FFFu + ((u >> 16) & 1u)) >> 16;  // RNE
  return (u16)r;
}

__device__ __forceinline__ void async_ld16(const void* g, void* l) {
  __builtin_amdgcn_global_load_lds(
      (__attribute__((address_space(1))) unsigned int*)g,
      (__attribute__((address_space(3))) unsigned int*)l, 16, 0, 0);
}

// ---------------- fp32 -> bf16 convert (grid-stride, float4) ----------------
__global__ void convert_kernel(const float4* __restrict__ src,
                               ushort4* __restrict__ dst, int n4) {
  int i = blockIdx.x * blockDim.x + threadIdx.x;
  int stride = gridDim.x * blockDim.x;
  for (; i < n4; i += stride) {
    float4 v = src[i];
    ushort4 o;
    o.x = f2bf(v.x); o.y = f2bf(v.y); o.z = f2bf(v.z); o.w = f2bf(v.w);
    dst[i] = o;
  }
}

// ---------------- fp32 proj GEMM: proj = x @ cosw^T + cosb ----------------
__global__ __launch_bounds__(256, 2) void proj_gemm(
    const float* __restrict__ x, const float* __restrict__ w,
    const float* __restrict__ b, float* __restrict__ proj) {
  __shared__ float Ats[32][68];  // [k][m], stride 68 floats
  __shared__ float Bts[32][68];  // [k][n]
  const int m0 = blockIdx.x * 64;
  const int n0 = blockIdx.y * 64;
  const int tid = threadIdx.x;
  const int tn = tid & 15, tm = tid >> 4;
  float acc[4][4] = {};
  for (int k0 = 0; k0 < DM; k0 += 32) {
#pragma unroll
    for (int u = 0; u < 2; u++) {
      int idx = tid + u * 256;
      int row = idx >> 3, kq = (idx & 7) * 4;
      float4 va = *(const float4*)&x[(size_t)(m0 + row) * DM + k0 + kq];
      Ats[kq + 0][row] = va.x; Ats[kq + 1][row] = va.y;
      Ats[kq + 2][row] = va.z; Ats[kq + 3][row] = va.w;
      float4 vb = *(const float4*)&w[(size_t)(n0 + row) * DM + k0 + kq];
      Bts[kq + 0][row] = vb.x; Bts[kq + 1][row] = vb.y;
      Bts[kq + 2][row] = vb.z; Bts[kq + 3][row] = vb.w;
    }
    __syncthreads();
#pragma unroll
    for (int kk = 0; kk < 32; kk++) {
      float4 av = *(const float4*)&Ats[kk][tm * 4];
      float4 bv = *(const float4*)&Bts[kk][tn * 4];
      float ar[4] = {av.x, av.y, av.z, av.w};
      float br[4] = {bv.x, bv.y, bv.z, bv.w};
#pragma unroll
      for (int i = 0; i < 4; i++)
#pragma unroll
        for (int j = 0; j < 4; j++) acc[i][j] = fmaf(ar[i], br[j], acc[i][j]);
    }
    __syncthreads();
  }
#pragma unroll
  for (int i = 0; i < 4; i++) {
    int row = m0 + tm * 4 + i;
#pragma unroll
    for (int j = 0; j < 4; j++) {
      int col = n0 + tn * 4 + j;
      proj[(size_t)row * PD + col] = acc[i][j] + b[col];
    }
  }
}

// ---------------- sim_matrix column l2norm: simn[p][e] ----------------
__global__ void simnorm_kernel(const float* __restrict__ sim,
                               float* __restrict__ simn) {
  __shared__ float partial[256];
  __shared__ float norms[8];
  int tid = threadIdx.x;
  int e = tid & 7, pg = tid >> 3;
  float s = 0.f;
#pragma unroll
  for (int i = 0; i < 8; i++) {
    float v = sim[(size_t)(pg + i * 32) * NE + e];
    s += v * v;
  }
  partial[tid] = s;
  __syncthreads();
  if (tid < 8) {
    float t = 0.f;
    for (int g = 0; g < 32; g++) t += partial[tid + 8 * g];
    norms[tid] = fmaxf(sqrtf(t), 1e-12f);
  }
  __syncthreads();
  for (int i = tid; i < PD * NE; i += 256) simn[i] = sim[i] / norms[i & 7];
}

// ---------------- gate: l2norm(proj) . simn * exp(T), top-2 softmax ----------------
__global__ void gate_kernel(const float* __restrict__ proj,
                            const float* __restrict__ simn,
                            const float* __restrict__ temp,
                            int* __restrict__ tok_e, float* __restrict__ tok_g,
                            int* __restrict__ counts) {
  int t = blockIdx.x * 4 + (threadIdx.x >> 6);
  int lane = threadIdx.x & 63;
  float4 v = *(const float4*)&proj[(size_t)t * PD + lane * 4];
  float nn = v.x * v.x + v.y * v.y + v.z * v.z + v.w * v.w;
#pragma unroll
  for (int o = 32; o; o >>= 1) nn += __shfl_xor(nn, o);
  float inv = 1.0f / fmaxf(sqrtf(nn), 1e-12f);
  float l[8];
  int p = lane * 4;
#pragma unroll
  for (int e = 0; e < 8; e++) {
    float s = v.x * simn[(size_t)p * NE + e] + v.y * simn[(size_t)(p + 1) * NE + e] +
              v.z * simn[(size_t)(p + 2) * NE + e] + v.w * simn[(size_t)(p + 3) * NE + e];
#pragma unroll
    for (int o = 32; o; o >>= 1) s += __shfl_xor(s, o);
    l[e] = s;
  }
  if (lane == 0) {
    float scale = inv * expf(temp[0]);
    float ll[8];
#pragma unroll
    for (int e = 0; e < 8; e++) ll[e] = l[e] * scale;
    int i0 = 0;
    float best = ll[0];
#pragma unroll
    for (int e = 1; e < 8; e++)
      if (ll[e] > best) { best = ll[e]; i0 = e; }
    int i1 = -1;
    float second = -1e30f;
#pragma unroll
    for (int e = 0; e < 8; e++)
      if (e != i0 && ll[e] > second) { second = ll[e]; i1 = e; }
    float ex = expf(second - best);
    float g0 = 1.f / (1.f + ex);
    float g1 = ex / (1.f + ex);
    tok_e[t * 2] = i0; tok_e[t * 2 + 1] = i1;
    tok_g[t * 2] = g0; tok_g[t * 2 + 1] = g1;
    atomicAdd(&counts[i0], 1);
    atomicAdd(&counts[i1], 1);
  }
}

// ---------------- scan: 128-aligned expert segments + mb map ----------------
__global__ void scan_kernel(const int* __restrict__ counts,
                            int* __restrict__ cursors,
                            int* __restrict__ mb_expert,
                            int* __restrict__ total_mb) {
  if (threadIdx.x == 0 && blockIdx.x == 0) {
    int mb = 0;
    for (int e = 0; e < NE; e++) {
      cursors[e] = mb * 128;
      int c = (counts[e] + 127) >> 7;
      for (int i = 0; i < c; i++) mb_expert[mb + i] = e;
      mb += c;
    }
    *total_mb = mb;
  }
}

// ---------------- fill: slot assignment + gather x -> bf16 Xg ----------------
__global__ void fill_gather(const float* __restrict__ x,
                            const int* __restrict__ tok_e,
                            const float* __restrict__ tok_g,
                            int* __restrict__ cursors,
                            int* __restrict__ slot_token,
                            float* __restrict__ slot_gate,
                            u16* __restrict__ Xg) {
  int t = blockIdx.x;
  __shared__ int s_slot[2];
  if (threadIdx.x < 2) {
    int s = threadIdx.x;
    int e = tok_e[t * 2 + s];
    int slot = atomicAdd(&cursors[e], 1);
    s_slot[s] = slot;
    slot_token[slot] = t;
    slot_gate[slot] = tok_g[t * 2 + s];
  }
  __syncthreads();
  float4 xv = *(const float4*)&x[(size_t)t * DM + threadIdx.x * 4];
  ushort4 bv;
  bv.x = f2bf(xv.x); bv.y = f2bf(xv.y); bv.z = f2bf(xv.z); bv.w = f2bf(xv.w);
  *(ushort4*)&Xg[(size_t)s_slot[0] * DM + threadIdx.x * 4] = bv;
  *(ushort4*)&Xg[(size_t)s_slot[1] * DM + threadIdx.x * 4] = bv;
}

// ---------------- bf16 MFMA GEMM, XOR-swizzled LDS ----------------
// LDS layout: 16B chunk c of tile-row r stored at byte (r*128 + (c ^ (r&7))*16).
// Staging: lane loads global chunk ((lane&7) ^ (lane>>3)) so data lands swizzled
// (global_load_lds dest is wave-uniform base + lane*16 — cannot pad, so permute
// the SOURCE). Reads: kofs chunk = (kk*4 + (lane>>4)) ^ (row&7), row&7 == lane&7
// for both A and B fragment rows -> 32 banks covered at 2 lanes/bank (free, m136).
// MODE 1: H = relu(A @ W[e]^T + bias[e])  -> bf16
// MODE 2: out[token] += gate * (A @ W[e]^T + bias[e])  (atomic scatter)
template <int KDIM, int MODE>
__global__ __launch_bounds__(256, 2) void moe_gemm(
    const u16* __restrict__ A, const u16* __restrict__ W,
    const float* __restrict__ bias, u16* __restrict__ Hout,
    float* __restrict__ Out, const int* __restrict__ mb_expert,
    const int* __restrict__ total_mb, const int* __restrict__ slot_token,
    const float* __restrict__ slot_gate, int NW) {
  const int mb = blockIdx.y;
  if (mb >= *total_mb) return;
  const int e = mb_expert[mb];
  const int nb = blockIdx.x;

  __shared__ u16 As[128 * 64];
  __shared__ u16 Bs[128 * 64];

  const int tid = threadIdx.x;
  const int lane = tid & 63;
  const int wv = tid >> 6;
  const int wm = wv >> 1, wn = wv & 1;

  const u16* Ab = A + (size_t)mb * 128 * KDIM;
  const u16* Bb = W + (size_t)e * NW * KDIM + (size_t)nb * 128 * KDIM;

  floatx4 acc[4][4] = {};

  const int r8 = lane >> 3;                      // row within 8-row group
  const int lo3 = lane & 7;
  const int c8 = (lo3 ^ r8) * 8;                 // XOR-swizzled source chunk
  const int q16 = lane & 15;
  const int hi2 = lane >> 4;

  for (int k0 = 0; k0 < KDIM; k0 += 64) {
#pragma unroll
    for (int i = 0; i < 4; i++) {
      int rowA = wv * 32 + i * 8;  // wave-uniform LDS base (multiple of 8)
      async_ld16(Ab + (size_t)(rowA + r8) * KDIM + k0 + c8, As + rowA * 64);
      async_ld16(Bb + (size_t)(rowA + r8) * KDIM + k0 + c8, Bs + rowA * 64);
    }
    __syncthreads();
#pragma unroll
    for (int kk = 0; kk < 2; kk++) {
      // swizzled chunk offset; row&7 == lane&7 for all fragment rows below
      const int kofs = ((kk * 4 + hi2) ^ lo3) * 8;
      bf16x8 af[4], bfr[4];
#pragma unroll
      for (int i = 0; i < 4; i++)
        af[i] = *(const bf16x8*)(As + (wm * 64 + i * 16 + q16) * 64 + kofs);
#pragma unroll
      for (int j = 0; j < 4; j++)
        bfr[j] = *(const bf16x8*)(Bs + (wn * 64 + j * 16 + q16) * 64 + kofs);
#pragma unroll
      for (int i = 0; i < 4; i++)
#pragma unroll
        for (int j = 0; j < 4; j++)
          acc[i][j] = __builtin_amdgcn_mfma_f32_16x16x32_bf16(af[i], bfr[j],
                                                              acc[i][j], 0, 0, 0);
    }
    __syncthreads();
  }

  const int col0 = nb * 128 + wn * 64;
  const int row0 = mb * 128 + wm * 64;
  if constexpr (MODE == 1) {
#pragma unroll
    for (int j = 0; j < 4; j++) {
      int col = col0 + j * 16 + q16;
      float bv = bias[(size_t)e * NW + col];
#pragma unroll
      for (int i = 0; i < 4; i++)
#pragma unroll
        for (int r = 0; r < 4; r++) {
          int row = row0 + i * 16 + hi2 * 4 + r;
          float v = acc[i][j][r] + bv;
          Hout[(size_t)row * NW + col] = f2bf(fmaxf(v, 0.f));
        }
    }
  } else {
#pragma unroll
    for (int i = 0; i < 4; i++)
#pragma unroll
      for (int r = 0; r < 4; r++) {
        int row = row0 + i * 16 + hi2 * 4 + r;
        int tok = slot_token[row];
        float g = slot_gate[row];
        if (tok >= 0) {
#pragma unroll
          for (int j = 0; j < 4; j++) {
            int col = col0 + j * 16 + q16;
            atomicAdd(&Out[(size_t)tok * DM + col],
                      g * (acc[i][j][r] + bias[(size_t)e * NW + col]));
          }
        }
      }
  }
}

extern "C" void kernel_launch(void* const* d_in, const int* in_sizes, int n_in,
                              void* d_out, int out_size, void* d_ws, size_t ws_size,
                              hipStream_t stream) {
  const float* x = (const float*)d_in[0];
  const float* cosw = (const float*)d_in[1];
  const float* cosb = (const float*)d_in[2];
  const float* simm = (const float*)d_in[3];
  const float* temp = (const float*)d_in[4];
  const float* fc1w = (const float*)d_in[5];
  const float* fc1b = (const float*)d_in[6];
  const float* fc2w = (const float*)d_in[7];
  const float* fc2b = (const float*)d_in[8];
  float* out = (float*)d_out;

  char* ws = (char*)d_ws;
  size_t off = 0;
  auto alloc = [&](size_t bytes) {
    void* p = ws + off;
    off = (off + bytes + 255) & ~(size_t)255;
    return p;
  };
  u16* fc1w_bf = (u16*)alloc((size_t)NE * DFF * DM * 2);       // 64 MiB
  u16* fc2w_bf = (u16*)alloc((size_t)NE * DM * DFF * 2);       // 64 MiB
  u16* Xg = (u16*)alloc((size_t)MAXROWS * DM * 2);             // 34 MiB
  u16* H = (u16*)alloc((size_t)MAXROWS * DFF * 2);             // 136 MiB
  float* proj = (float*)alloc((size_t)NTOK * PD * 4);
  float* simn = (float*)alloc((size_t)PD * NE * 4);
  int* tok_e = (int*)alloc((size_t)NTOK * 2 * 4);
  float* tok_g = (float*)alloc((size_t)NTOK * 2 * 4);
  int* slot_token = (int*)alloc((size_t)MAXROWS * 4);
  float* slot_gate = (float*)alloc((size_t)MAXROWS * 4);
  int* counts = (int*)alloc(8 * 4);
  int* cursors = (int*)alloc(8 * 4);
  int* mb_expert = (int*)alloc(MAXMB * 4);
  int* total_mb = (int*)alloc(4);
  if (off > ws_size) return;

  hipMemsetAsync(counts, 0, 32, stream);
  hipMemsetAsync(slot_token, 0xFF, (size_t)MAXROWS * 4, stream);      // -1
  hipMemsetAsync(Xg, 0, (size_t)MAXROWS * DM * 2, stream);            // zero pads
  hipMemsetAsync(out, 0, (size_t)NTOK * DM * 4, stream);

  convert_kernel<<<4096, 256, 0, stream>>>((const float4*)fc1w,
                                           (ushort4*)fc1w_bf, NE * DFF * DM / 4);
  convert_kernel<<<4096, 256, 0, stream>>>((const float4*)fc2w,
                                           (ushort4*)fc2w_bf, NE * DM * DFF / 4);

  proj_gemm<<<dim3(NTOK / 64, PD / 64), 256, 0, stream>>>(x, cosw, cosb, proj);
  simnorm_kernel<<<1, 256, 0, stream>>>(simm, simn);
  gate_kernel<<<NTOK / 4, 256, 0, stream>>>(proj, simn, temp, tok_e, tok_g, counts);

  scan_kernel<<<1, 1, 0, stream>>>(counts, cursors, mb_expert, total_mb);
  fill_gather<<<NTOK, 256, 0, stream>>>(x, tok_e, tok_g, cursors, slot_token,
                                        slot_gate, Xg);

  moe_gemm<DM, 1><<<dim3(DFF / 128, MAXMB), 256, 0, stream>>>(
      Xg, fc1w_bf, fc1b, H, nullptr, mb_expert, total_mb, nullptr, nullptr, DFF);
  moe_gemm<DFF, 2><<<dim3(DM / 128, MAXMB), 256, 0, stream>>>(
      H, fc2w_bf, fc2b, nullptr, out, mb_expert, total_mb, slot_token, slot_gate, DM);
}